// Round 7
// baseline (101.153 us; speedup 1.0000x reference)
//
#include <hip/hip_runtime.h>
#include <hip/hip_bf16.h>

// ---- problem constants ----
#define B_IMG   128
#define CH      3
#define HW      224
#define NPATCH  196          // tokens per image
#define TOKENS  25088        // B_IMG * NPATCH
#define PATCH   16
#define FDIM    768          // C*P*P (K of the GEMM)
#define DDIM    768          // output embed dim (N of the GEMM)
#define TOKELEMS ((size_t)TOKENS * FDIM)
#define OUT_TOKENS ((size_t)TOKENS * DDIM)     // positions follow in d_out

#define GATHER_BLOCKS (TOKENS * (FDIM / 4) / 256)   // 18816
#define WCONV_BLOCKS  ((DDIM * FDIM / 4) / 256)     // 576

typedef short short8 __attribute__((ext_vector_type(8)));
typedef float f32x4  __attribute__((ext_vector_type(4)));

static __device__ __forceinline__ unsigned short f2bf(float v) {
  unsigned u = __float_as_uint(v);
  unsigned r = u + 0x7fffu + ((u >> 16) & 1u);
  return (unsigned short)(r >> 16);
}

static __device__ __forceinline__ void gload16(const short* g, short* l) {
  __builtin_amdgcn_global_load_lds(
      (const __attribute__((address_space(1))) void*)g,
      (__attribute__((address_space(3))) void*)l,
      16, 0, 0);
}

// ---- kernel 1: gather patches -> bf16 [TOKENS][768] + positions, W -> bf16 ----
__global__ __launch_bounds__(256) void prep_kernel(
    const float* __restrict__ x, const int* __restrict__ ys,
    const int* __restrict__ xs, const float* __restrict__ W,
    short* __restrict__ patches, short* __restrict__ Wbf,
    float* __restrict__ pos) {
  const int blk = blockIdx.x;
  if (blk < GATHER_BLOCKS) {
    int e   = blk * 256 + threadIdx.x;      // quad index
    int tok = e / 192;
    int q   = e - tok * 192;
    int f   = q * 4;
    int b   = tok / NPATCH;
    int y   = ys[tok];
    int xc  = xs[tok];
    int c   = f >> 8;
    int rem = f & 255;
    int py  = rem >> 4;
    int px  = rem & 15;
    const float* src = x + ((size_t)(b * CH + c) * HW + (y + py)) * HW + xc + px;
    ushort4 o;
    o.x = f2bf(src[0]); o.y = f2bf(src[1]); o.z = f2bf(src[2]); o.w = f2bf(src[3]);
    *(ushort4*)&patches[(size_t)tok * FDIM + f] = o;
    if (q == 0) {
      pos[(size_t)tok * 2]     = (float)y;
      pos[(size_t)tok * 2 + 1] = (float)xc;
    }
  } else {
    int i = ((blk - GATHER_BLOCKS) * 256 + threadIdx.x) * 4;
    float4 v = *(const float4*)&W[i];
    ushort4 o;
    o.x = f2bf(v.x); o.y = f2bf(v.y); o.z = f2bf(v.z); o.w = f2bf(v.w);
    *(ushort4*)&Wbf[i] = o;
  }
}

// ---- kernel 2: 128x256 8-wave ring-3 pipelined MFMA GEMM ----
// Per step s: stage(s+3) -> vmcnt(6) [s+1 landed, 2-iter slack] -> barrier ->
// ds_read frags(s+1) into ALTERNATE reg set || 16 MFMA on tile s's regs
// (no wait between: counted overlap, the actual T3/T4 mechanism) ->
// lgkmcnt(0) + sched_barrier (rule #18) -> barrier.
// Slot safety: STEP(s) overwrites slot s%3 whose frags were read at
// STEP(s-1), fenced by that step's lgkm0 + closing barrier.
__global__ __launch_bounds__(512) void gemm_kernel(
    const short* __restrict__ A,    // patches bf16 [TOKENS][768]
    const short* __restrict__ Bw,   // Wbf bf16 [768][768]
    const float* __restrict__ bias,
    float* __restrict__ C) {
  __shared__ short As[3][128 * 32];   // 8KB/slot
  __shared__ short Bs[3][256 * 32];   // 16KB/slot  -> 72KB total

  const int tid = threadIdx.x;
  const int w   = tid >> 6;      // 0..7
  const int l   = tid & 63;
  const int wr  = w >> 2;        // 0..1 : M half (64 rows each)
  const int wc  = w & 3;         // 0..3 : N quarter (64 cols each)
  const int lr  = l & 15;
  const int lg  = l >> 4;

  // bijective XCD swizzle, 588 blocks = 4 chunks of 74 + 4 of 73 (m204).
  // nt inner => the 3 N-siblings of an A-panel are consecutive on one XCD.
  const int id   = blockIdx.x;
  const int xcd  = id & 7;
  const int chnk = id >> 3;
  const int nid  = (xcd < 4 ? xcd * 74 : 4 * 74 + (xcd - 4) * 73) + chnk;
  const int mt   = nid / 3;
  const int nt   = nid - mt * 3;
  const int m0   = mt * 128;
  const int n0   = nt * 256;

  // bias pinned complete before staging (keeps the per-wave vmcnt queue clean)
  float bs[4];
#pragma unroll
  for (int ni = 0; ni < 4; ++ni)
    bs[ni] = bias[n0 + wc * 64 + ni * 16 + lr];
#pragma unroll
  for (int ni = 0; ni < 4; ++ni) asm volatile("" : "+v"(bs[ni]));

  f32x4 acc[4][4];
  const f32x4 z = {0.f, 0.f, 0.f, 0.f};
#pragma unroll
  for (int mi = 0; mi < 4; ++mi)
#pragma unroll
    for (int ni = 0; ni < 4; ++ni) acc[mi][ni] = z;

  // staging: per iter each wave issues exactly 3 gload16:
  //   A: 16 rows [m0 + w*16, +16)   (1 op)
  //   B: 32 rows [n0 + w*32, +32)   (2 ops)
  const short* gA = A  + (size_t)(m0 + w * 16 + (l >> 2)) * FDIM + ((l & 3) << 3);
  const short* gB = Bw + (size_t)(n0 + w * 32 + (l >> 2)) * FDIM + ((l & 3) << 3);
  const int lA = (w * 16) * 32;   // shorts; gload_lds adds lane*8
  const int lB = (w * 32) * 32;

  short8 f0[8], f1[8];   // [0..3]=A frags, [4..7]=B frags — two named sets

#define STAGE(SLOT, KT)                                                   \
  do {                                                                    \
    const int ko_ = (KT) * 32;                                            \
    gload16(gA + ko_, &As[(SLOT)][lA]);                                   \
    gload16(gB + ko_, &Bs[(SLOT)][lB]);                                   \
    gload16(gB + 16 * FDIM + ko_, &Bs[(SLOT)][lB + 16 * 32]);             \
  } while (0)

#define READF(SLOT, F)                                                    \
  do {                                                                    \
    const int rs_ = (SLOT);                                               \
    _Pragma("unroll")                                                     \
    for (int mi = 0; mi < 4; ++mi)                                        \
      F[mi] = *(const short8*)&As[rs_][(wr * 64 + mi * 16 + lr) * 32 + lg * 8]; \
    _Pragma("unroll")                                                     \
    for (int ni = 0; ni < 4; ++ni)                                        \
      F[4 + ni] = *(const short8*)&Bs[rs_][(wc * 64 + ni * 16 + lr) * 32 + lg * 8]; \
  } while (0)

#define MFMAC(F)                                                          \
  do {                                                                    \
    __builtin_amdgcn_s_setprio(1);                                        \
    _Pragma("unroll")                                                     \
    for (int mi = 0; mi < 4; ++mi)                                        \
      _Pragma("unroll")                                                   \
      for (int ni = 0; ni < 4; ++ni)                                      \
        acc[mi][ni] = __builtin_amdgcn_mfma_f32_16x16x32_bf16(            \
            F[mi], F[4 + ni], acc[mi][ni], 0, 0, 0);                      \
    __builtin_amdgcn_s_setprio(0);                                        \
  } while (0)

#define STEP(S, CUR, NXT, DOSTAGE, VMIMM)                                 \
  do {                                                                    \
    if (DOSTAGE) STAGE((S) % 3, (S) + 3);                                 \
    asm volatile("s_waitcnt vmcnt(" #VMIMM ")" ::: "memory");             \
    __builtin_amdgcn_s_barrier();                                         \
    READF(((S) + 1) % 3, NXT);                                            \
    MFMAC(CUR);                                                           \
    asm volatile("s_waitcnt lgkmcnt(0)" ::: "memory");                    \
    __builtin_amdgcn_sched_barrier(0);                                    \
    __builtin_amdgcn_s_barrier();                                         \
  } while (0)

  // prologue: 3 tiles in flight (9 ops/wave), tile0 -> f0
  STAGE(0, 0);
  STAGE(1, 1);
  STAGE(2, 2);
  asm volatile("s_waitcnt vmcnt(6)" ::: "memory");   // tile 0 landed
  __builtin_amdgcn_s_barrier();
  READF(0, f0);
  asm volatile("s_waitcnt lgkmcnt(0)" ::: "memory");
  __builtin_amdgcn_sched_barrier(0);
  __builtin_amdgcn_s_barrier();

#pragma unroll 1
  for (int s = 0; s < 20; s += 2) {
    STEP(s,     f0, f1, true, 6);
    STEP(s + 1, f1, f0, true, 6);
  }
  STEP(20, f0, f1, true,  6);
  STEP(21, f1, f0, false, 3);
  STEP(22, f0, f1, false, 0);
  MFMAC(f1);                       // tile 23

  // epilogue: C/D layout col = lane&15, row = (lane>>4)*4 + j
#pragma unroll
  for (int ni = 0; ni < 4; ++ni) {
    const int col = n0 + wc * 64 + ni * 16 + lr;
#pragma unroll
    for (int mi = 0; mi < 4; ++mi) {
      const int row = m0 + wr * 64 + mi * 16 + lg * 4;
      const f32x4 v = acc[mi][ni];
#pragma unroll
      for (int j = 0; j < 4; ++j)
        C[(size_t)(row + j) * DDIM + col] = v[j] + bs[ni];
    }
  }
#undef STAGE
#undef READF
#undef MFMAC
#undef STEP
}

// ---- fallback (ws too small): naive fused f32, correct but slow ----
__global__ __launch_bounds__(256) void naive_kernel(
    const float* __restrict__ x, const int* __restrict__ ys,
    const int* __restrict__ xs, const float* __restrict__ W,
    const float* __restrict__ bias, float* __restrict__ out) {
  __shared__ float prow[FDIM];
  const int tok = blockIdx.x;
  const int t   = threadIdx.x;
  const int b   = tok / NPATCH;
  const int y   = ys[tok];
  const int xc  = xs[tok];
  for (int i = t; i < FDIM; i += 256) {
    int c = i >> 8, rem = i & 255, py = rem >> 4, px = rem & 15;
    prow[i] = x[((size_t)(b * CH + c) * HW + y + py) * HW + xc + px];
  }
  __syncthreads();
  for (int dd = 0; dd < 3; ++dd) {
    const int d = t + dd * 256;
    float s = bias[d];
    const float4* wr = (const float4*)&W[(size_t)d * FDIM];
    const float4* pr = (const float4*)prow;
    for (int f4 = 0; f4 < FDIM / 4; ++f4) {
      float4 wv = wr[f4];
      float4 pv = pr[f4];
      s += wv.x * pv.x + wv.y * pv.y + wv.z * pv.z + wv.w * pv.w;
    }
    out[(size_t)tok * DDIM + d] = s;
  }
  if (t == 0) {
    float* pos = out + OUT_TOKENS;
    pos[(size_t)tok * 2]     = (float)y;
    pos[(size_t)tok * 2 + 1] = (float)xc;
  }
}

extern "C" void kernel_launch(void* const* d_in, const int* in_sizes, int n_in,
                              void* d_out, int out_size, void* d_ws, size_t ws_size,
                              hipStream_t stream) {
  const float* x    = (const float*)d_in[0];
  const int*   ys   = (const int*)d_in[1];
  const int*   xs   = (const int*)d_in[2];
  const float* W    = (const float*)d_in[3];
  const float* bias = (const float*)d_in[4];
  float* out = (float*)d_out;
  float* pos = out + OUT_TOKENS;

  const size_t w_bytes = (size_t)DDIM * FDIM * 2;
  const size_t p_bytes = TOKELEMS * 2;
  if (ws_size >= w_bytes + p_bytes) {
    short* Wbf     = (short*)d_ws;
    short* patches = (short*)d_ws + (size_t)DDIM * FDIM;
    prep_kernel<<<GATHER_BLOCKS + WCONV_BLOCKS, 256, 0, stream>>>(
        x, ys, xs, W, patches, Wbf, pos);
    gemm_kernel<<<(TOKENS / 128) * (DDIM / 256), 512, 0, stream>>>(
        patches, Wbf, bias, out);
  } else {
    naive_kernel<<<TOKENS, 256, 0, stream>>>(x, ys, xs, W, bias, out);
  }
}